// Round 2
// baseline (25.811 us; speedup 1.0000x reference)
//
#include <hip/hip_runtime.h>
#include <stdint.h>

#define S 2048
#define B 256
#define H 8
#define NPER 12
#define NPOS 11
#define THRESH 4

// ws layout:
//  [0,       65536)   packed_tokens : S*4 u64   (64 KB)
//  [65536,   98304)   qc_u16        : S*8 u16   (32 KB)
//  [98304,  131072)   kc_u16        : S*8 u16   (32 KB)
//  [131072, 163840)   pc_u16        : S*8 u16   (32 KB)
//  [163840, 167936)   packed_table  : 512 u64   ( 4 KB)

__global__ void pack_table_kernel(const int* __restrict__ table,
                                  uint64_t* __restrict__ ptab) {
    int k = blockIdx.x * blockDim.x + threadIdx.x;   // 0..511
    if (k < 512) {
        int h = k >> 6, w = k & 63;
        const int* src = table + h * 4096 + w * 64;
        uint64_t v = 0;
        #pragma unroll 8
        for (int b = 0; b < 64; ++b) v |= (uint64_t)(src[b] & 1) << b;
        ptab[k] = v;
    }
}

// one block per row i: ballot-pack tokens row, compute q/k/p contribs
__global__ void precompute_kernel(const int* __restrict__ tokens,
                                  const int* __restrict__ conn,
                                  uint64_t* __restrict__ packed_tokens,
                                  uint16_t* __restrict__ qc,
                                  uint16_t* __restrict__ kc,
                                  uint16_t* __restrict__ pc) {
    __shared__ uint64_t srow[4];
    const int i = blockIdx.x;
    const int tid = threadIdx.x;
    const int lane = tid & 63, wave = tid >> 6;

    int t = tokens[i * B + tid];
    uint64_t m = __ballot(t != 0);
    if (lane == 0) {
        srow[wave] = m;
        packed_tokens[i * 4 + wave] = m;
    }
    __syncthreads();

    if (tid < H) {
        int h = tid;
        int q = 0, k = 0, p = 0;
        #pragma unroll
        for (int n = 0; n < NPER; ++n) {
            int c = conn[h * NPER + n];
            if (c < B) {
                int bit = (int)((srow[c >> 6] >> (c & 63)) & 1);
                q |= bit << n;
            } else if (c < 2 * B) {
                int cc = c - B;
                int bit = (int)((srow[cc >> 6] >> (cc & 63)) & 1);
                k |= bit << n;
            } else {
                int idx = c - 2 * B;           // in [0, NPOS)
                int bit = (i >> idx) & 1;      // rel_bits[d=i, idx]
                p |= bit << n;
            }
        }
        qc[i * 8 + h] = (uint16_t)q;
        kc[i * 8 + h] = (uint16_t)k;
        pc[i * 8 + h] = (uint16_t)p;
    }
}

__launch_bounds__(256)
__global__ void main_kernel(const uint64_t* __restrict__ packed_tokens,
                            const uint16_t* __restrict__ qc,
                            const uint16_t* __restrict__ kc,
                            const uint16_t* __restrict__ pc,
                            const uint64_t* __restrict__ ptab,
                            int* __restrict__ out) {
    __shared__ uint64_t s_table[512];
    __shared__ uint64_t s_xor[4][4];
    __shared__ int s_key[4];
    __shared__ int s_any[4];

    const int i = blockIdx.x;
    const int tid = threadIdx.x;
    const int lane = tid & 63, wave = tid >> 6;

    for (int k = tid; k < 512; k += 256) s_table[k] = ptab[k];
    __syncthreads();

    const uint64_t* qv = (const uint64_t*)(qc + i * 8);
    const uint64_t q0 = qv[0], q1 = qv[1];

    uint64_t x0 = 0, x1 = 0, x2 = 0, x3 = 0;
    int bestv = -1, bestj = 0;
    int any = 0;

    for (int j = tid; j <= i; j += 256) {
        const uint64_t* kv = (const uint64_t*)(kc + j * 8);
        const uint64_t* pv = (const uint64_t*)(pc + (i - j) * 8);
        // 8 heads x 16-bit lanes; q/k/p occupy disjoint bits -> no carry
        uint64_t a0 = q0 + kv[0] + pv[0];
        uint64_t a1 = q1 + kv[1] + pv[1];
        int vote = 0;
        #pragma unroll
        for (int h = 0; h < 4; ++h) {
            int addr = (int)((a0 >> (16 * h)) & 0xFFF);
            vote += (int)((s_table[h * 64 + (addr >> 6)] >> (addr & 63)) & 1);
        }
        #pragma unroll
        for (int h = 0; h < 4; ++h) {
            int addr = (int)((a1 >> (16 * h)) & 0xFFF);
            vote += (int)((s_table[(h + 4) * 64 + (addr >> 6)] >> (addr & 63)) & 1);
        }
        if (vote >= THRESH) {
            any = 1;
            const uint64_t* pt = packed_tokens + j * 4;
            x0 ^= pt[0]; x1 ^= pt[1]; x2 ^= pt[2]; x3 ^= pt[3];
        }
        if (vote > bestv) { bestv = vote; bestj = j; }   // strict > keeps min j per thread
    }

    // key: higher vote wins; tie -> smaller j (first occurrence, matches argmax)
    int key = ((bestv + 1) << 16) | (2047 - bestj);
    uint64_t anym = __ballot(any != 0);

    #pragma unroll
    for (int off = 32; off > 0; off >>= 1) {
        key = max(key, __shfl_xor(key, off));
        x0 ^= __shfl_xor(x0, off);
        x1 ^= __shfl_xor(x1, off);
        x2 ^= __shfl_xor(x2, off);
        x3 ^= __shfl_xor(x3, off);
    }

    if (lane == 0) {
        s_xor[wave][0] = x0; s_xor[wave][1] = x1;
        s_xor[wave][2] = x2; s_xor[wave][3] = x3;
        s_key[wave] = key;
        s_any[wave] = (anym != 0ull) ? 1 : 0;
    }
    __syncthreads();

    if (tid == 0) {
        int fk = s_key[0];
        int fa = s_any[0];
        uint64_t f0 = s_xor[0][0], f1 = s_xor[0][1], f2 = s_xor[0][2], f3 = s_xor[0][3];
        #pragma unroll
        for (int w = 1; w < 4; ++w) {
            fk = max(fk, s_key[w]);
            fa |= s_any[w];
            f0 ^= s_xor[w][0]; f1 ^= s_xor[w][1]; f2 ^= s_xor[w][2]; f3 ^= s_xor[w][3];
        }
        s_key[0] = fk; s_any[0] = fa;
        s_xor[0][0] = f0; s_xor[0][1] = f1; s_xor[0][2] = f2; s_xor[0][3] = f3;
    }
    __syncthreads();

    const int b = tid;
    int o;
    if (s_any[0]) {
        o = (int)((s_xor[0][b >> 6] >> (b & 63)) & 1);
    } else {
        int bj = 2047 - (s_key[0] & 0xFFFF);
        o = (int)((packed_tokens[bj * 4 + (b >> 6)] >> (b & 63)) & 1);
    }
    out[i * B + b] = o;
}

extern "C" void kernel_launch(void* const* d_in, const int* in_sizes, int n_in,
                              void* d_out, int out_size, void* d_ws, size_t ws_size,
                              hipStream_t stream) {
    const int* tokens = (const int*)d_in[0];
    const int* conn   = (const int*)d_in[1];
    const int* table  = (const int*)d_in[2];
    int* out = (int*)d_out;

    uint8_t* ws = (uint8_t*)d_ws;
    uint64_t* packed_tokens = (uint64_t*)(ws);
    uint16_t* qc   = (uint16_t*)(ws + 65536);
    uint16_t* kc   = (uint16_t*)(ws + 98304);
    uint16_t* pc   = (uint16_t*)(ws + 131072);
    uint64_t* ptab = (uint64_t*)(ws + 163840);

    pack_table_kernel<<<2, 256, 0, stream>>>(table, ptab);
    precompute_kernel<<<S, 256, 0, stream>>>(tokens, conn, packed_tokens, qc, kc, pc);
    main_kernel<<<S, 256, 0, stream>>>(packed_tokens, qc, kc, pc, ptab, out);
}

// Round 3
// 22.027 us; speedup vs baseline: 1.1718x; 1.1718x over previous
//
#include <hip/hip_runtime.h>
#include <stdint.h>

#define S 2048
#define B 256
#define H 8
#define NPER 12
#define NPOS 11
#define THRESH 4

typedef unsigned long long u64;
typedef uint32_t u32;

// ws layout:
//  [0,       65536)   packed_tokens : S*4 u64   (64 KB)
//  [65536,   98304)   qc_u16        : S*8 u16   (32 KB)
//  [98304,  131072)   kc_u16        : S*8 u16   (32 KB)
//  [131072, 163840)   pc_u16        : S*8 u16   (32 KB)
//  [163840, 167936)   packed_table  : 512 u64   ( 4 KB)

// blocks 0..S-1: per-row token pack + q/k/p contribs; blocks S..S+1: table bitpack
__global__ void prep_kernel(const int* __restrict__ tokens,
                            const int* __restrict__ conn,
                            const int* __restrict__ table,
                            u64* __restrict__ packed_tokens,
                            uint16_t* __restrict__ qc,
                            uint16_t* __restrict__ kc,
                            uint16_t* __restrict__ pc,
                            u64* __restrict__ ptab) {
    const int bi = blockIdx.x;
    const int tid = threadIdx.x;

    if (bi >= S) {
        int k = (bi - S) * 256 + tid;          // 0..511
        int h = k >> 6, w = k & 63;
        const int* src = table + h * 4096 + w * 64;
        u64 v = 0;
        #pragma unroll 8
        for (int b = 0; b < 64; ++b) v |= (u64)(src[b] & 1) << b;
        ptab[k] = v;
        return;
    }

    __shared__ u64 srow[4];
    const int i = bi;
    const int lane = tid & 63, wave = tid >> 6;

    int t = tokens[i * B + tid];
    u64 m = __ballot(t != 0);
    if (lane == 0) {
        srow[wave] = m;
        packed_tokens[i * 4 + wave] = m;
    }
    __syncthreads();

    if (tid < H) {
        int h = tid;
        int q = 0, k = 0, p = 0;
        #pragma unroll
        for (int n = 0; n < NPER; ++n) {
            int c = conn[h * NPER + n];
            if (c < B) {
                q |= (int)((srow[c >> 6] >> (c & 63)) & 1) << n;
            } else if (c < 2 * B) {
                int cc = c - B;
                k |= (int)((srow[cc >> 6] >> (cc & 63)) & 1) << n;
            } else {
                int idx = c - 2 * B;            // [0, NPOS)
                p |= ((i >> idx) & 1) << n;
            }
        }
        qc[i * 8 + h] = (uint16_t)q;
        kc[i * 8 + h] = (uint16_t)k;
        pc[i * 8 + h] = (uint16_t)p;
    }
}

__launch_bounds__(256)
__global__ void main_kernel(const u64* __restrict__ packed_tokens,
                            const uint16_t* __restrict__ qc,
                            const uint16_t* __restrict__ kc,
                            const uint16_t* __restrict__ pc,
                            const u64* __restrict__ ptab,
                            int* __restrict__ out) {
    __shared__ u32 s_tab[1024];                 // head h at [h*128, (h+1)*128)
    __shared__ u64 s_xor[4][4];
    __shared__ int s_key[4];
    __shared__ int s_any[4];

    const int tid = threadIdx.x;
    const int lane = tid & 63, wave = tid >> 6;

    ((uint4*)s_tab)[tid] = ((const uint4*)ptab)[tid];   // 4 KB table -> LDS
    __syncthreads();

    auto do_row = [&](int i) {
        const u64* qv = (const u64*)(qc + i * 8);
        const u64 q0 = qv[0], q1 = qv[1];

        u64 x0 = 0, x1 = 0, x2 = 0, x3 = 0;
        int bestv = -1, bestj = 0, any = 0;

        const int niter = (i + 512) >> 9;       // ceil((i+1)/512)
        for (int it = 0; it < niter; ++it) {
            const int ja = tid + (it << 9);
            const int jb = ja + 256;
            const int jca = min(ja, i), jcb = min(jb, i);
            const int da = i - jca, db = i - jcb;

            // issue all loads up front (clamped -> always valid)
            const ulonglong2 kA = *(const ulonglong2*)(kc + jca * 8);
            const ulonglong2 pA = *(const ulonglong2*)(pc + da * 8);
            const ulonglong2 kB = *(const ulonglong2*)(kc + jcb * 8);
            const ulonglong2 pB = *(const ulonglong2*)(pc + db * 8);
            const ulonglong2 tA0 = *(const ulonglong2*)(packed_tokens + jca * 4);
            const ulonglong2 tA1 = *(const ulonglong2*)(packed_tokens + jca * 4 + 2);
            const ulonglong2 tB0 = *(const ulonglong2*)(packed_tokens + jcb * 4);
            const ulonglong2 tB1 = *(const ulonglong2*)(packed_tokens + jcb * 4 + 2);

            const u64 aa0 = q0 + kA.x + pA.x, aa1 = q1 + kA.y + pA.y;
            const u64 ab0 = q0 + kB.x + pB.x, ab1 = q1 + kB.y + pB.y;

            int vA = 0, vB = 0;
            #pragma unroll
            for (int h = 0; h < 4; ++h) {
                { u32 w = (u32)(aa0 >> (16 * h + 5)) & 127;
                  vA += (int)((s_tab[h * 128 + w] >> ((u32)(aa0 >> (16 * h)) & 31)) & 1); }
                { u32 w = (u32)(aa1 >> (16 * h + 5)) & 127;
                  vA += (int)((s_tab[(h + 4) * 128 + w] >> ((u32)(aa1 >> (16 * h)) & 31)) & 1); }
                { u32 w = (u32)(ab0 >> (16 * h + 5)) & 127;
                  vB += (int)((s_tab[h * 128 + w] >> ((u32)(ab0 >> (16 * h)) & 31)) & 1); }
                { u32 w = (u32)(ab1 >> (16 * h + 5)) & 127;
                  vB += (int)((s_tab[(h + 4) * 128 + w] >> ((u32)(ab1 >> (16 * h)) & 31)) & 1); }
            }

            const bool actA = (ja <= i), actB = (jb <= i);
            const bool incA = actA && (vA >= THRESH);
            const bool incB = actB && (vB >= THRESH);
            const u64 mA = incA ? ~0ull : 0ull;
            const u64 mB = incB ? ~0ull : 0ull;
            x0 ^= (tA0.x & mA) ^ (tB0.x & mB);
            x1 ^= (tA0.y & mA) ^ (tB0.y & mB);
            x2 ^= (tA1.x & mA) ^ (tB1.x & mB);
            x3 ^= (tA1.y & mA) ^ (tB1.y & mB);
            any |= (int)incA | (int)incB;

            const int kvA = actA ? vA : -1;
            const int kvB = actB ? vB : -1;
            if (kvA > bestv) { bestv = kvA; bestj = ja; }   // strict >: earliest j wins ties
            if (kvB > bestv) { bestv = kvB; bestj = jb; }
        }

        int key = ((bestv + 1) << 16) | (2047 - bestj);
        u64 anym = __ballot(any != 0);
        #pragma unroll
        for (int off = 32; off > 0; off >>= 1) {
            key = max(key, __shfl_xor(key, off));
            x0 ^= __shfl_xor(x0, off);
            x1 ^= __shfl_xor(x1, off);
            x2 ^= __shfl_xor(x2, off);
            x3 ^= __shfl_xor(x3, off);
        }

        if (lane == 0) {
            s_xor[wave][0] = x0; s_xor[wave][1] = x1;
            s_xor[wave][2] = x2; s_xor[wave][3] = x3;
            s_key[wave] = key;
            s_any[wave] = (anym != 0ull) ? 1 : 0;
        }
        __syncthreads();

        const int fk = max(max(s_key[0], s_key[1]), max(s_key[2], s_key[3]));
        const int fa = s_any[0] | s_any[1] | s_any[2] | s_any[3];
        const int widx = tid >> 6, bitb = tid & 63;
        const u64 xw = s_xor[0][widx] ^ s_xor[1][widx] ^ s_xor[2][widx] ^ s_xor[3][widx];
        int o;
        if (fa) {
            o = (int)((xw >> bitb) & 1);
        } else {
            const int bj = 2047 - (fk & 0xFFFF);
            o = (int)((packed_tokens[bj * 4 + widx] >> bitb) & 1);
        }
        out[i * B + tid] = o;
        __syncthreads();                         // s_* reused by next row
    };

    const int b = blockIdx.x;                    // 0..1023
    do_row(b);
    do_row(2047 - b);
}

extern "C" void kernel_launch(void* const* d_in, const int* in_sizes, int n_in,
                              void* d_out, int out_size, void* d_ws, size_t ws_size,
                              hipStream_t stream) {
    const int* tokens = (const int*)d_in[0];
    const int* conn   = (const int*)d_in[1];
    const int* table  = (const int*)d_in[2];
    int* out = (int*)d_out;

    uint8_t* ws = (uint8_t*)d_ws;
    u64* packed_tokens = (u64*)(ws);
    uint16_t* qc = (uint16_t*)(ws + 65536);
    uint16_t* kc = (uint16_t*)(ws + 98304);
    uint16_t* pc = (uint16_t*)(ws + 131072);
    u64* ptab    = (u64*)(ws + 163840);

    prep_kernel<<<S + 2, 256, 0, stream>>>(tokens, conn, table,
                                           packed_tokens, qc, kc, pc, ptab);
    main_kernel<<<S / 2, 256, 0, stream>>>(packed_tokens, qc, kc, pc, ptab, out);
}